// Round 7
// baseline (199.535 us; speedup 1.0000x reference)
//
#include <hip/hip_runtime.h>
#include <math.h>

#define BB 8
#define CC 512
#define LL 1024
#define GG 32
#define CPG 16
#define NH 8
#define CH 64

typedef unsigned short ushort_t;
typedef __attribute__((ext_vector_type(8))) short short8;
typedef __attribute__((ext_vector_type(4))) float f32x4;

#define SCALE_Q 0.18033688f  // 0.125 * log2(e)

__device__ inline ushort_t f2bf(float f) {
  union { float f; unsigned u; } v;
  v.f = f;
  unsigned r = v.u + 0x7FFFu + ((v.u >> 16) & 1u);
  return (ushort_t)(r >> 16);
}

// pack two f32 -> two bf16 (truncate) in one v_perm_b32
__device__ inline unsigned pack_bf2(float lo, float hi) {
  return __builtin_amdgcn_perm(__float_as_uint(hi), __float_as_uint(lo),
                               0x07060302u);
}

// XOR-swizzled LDS index: rows of 64 bf16, 8-elt groups swizzled by row.
__device__ inline int swz(int r, int k) {
  return r * 64 + ((((k >> 3) ^ (r & 7)) << 3) | (k & 7));
}

// ---------------- GroupNorm stats -> per-(b,c) scale/shift ----------------
__global__ __launch_bounds__(256) void gn_stats_kernel(
    const float* __restrict__ x, const float* __restrict__ gn_w,
    const float* __restrict__ gn_b, float* __restrict__ s_bc,
    float* __restrict__ t_bc) {
  int b = blockIdx.x / GG;
  int g = blockIdx.x % GG;
  const float* xg = x + ((size_t)b * CC + (size_t)g * CPG) * LL;
  float sum = 0.f, sq = 0.f;
  for (int i = threadIdx.x; i < CPG * LL; i += 256) {
    float v = xg[i];
    sum += v;
    sq += v * v;
  }
#pragma unroll
  for (int off = 32; off > 0; off >>= 1) {
    sum += __shfl_down(sum, off);
    sq += __shfl_down(sq, off);
  }
  __shared__ float red[8];
  __shared__ float st[2];
  int wave = threadIdx.x >> 6;
  if ((threadIdx.x & 63) == 0) {
    red[wave] = sum;
    red[4 + wave] = sq;
  }
  __syncthreads();
  if (threadIdx.x == 0) {
    float s = red[0] + red[1] + red[2] + red[3];
    float q = red[4] + red[5] + red[6] + red[7];
    float mean = s * (1.f / (CPG * LL));
    float var = q * (1.f / (CPG * LL)) - mean * mean;
    st[0] = mean;
    st[1] = rsqrtf(var + 1e-5f);
  }
  __syncthreads();
  if (threadIdx.x < CPG) {
    int c = g * CPG + threadIdx.x;
    float w = gn_w[c];
    float sc = st[1] * w;
    s_bc[b * CC + c] = sc;
    t_bc[b * CC + c] = gn_b[c] - st[0] * sc;
  }
}

// ---------------- weights fp32 -> bf16 ----------------
__global__ __launch_bounds__(256) void convert_w_kernel(
    const float* __restrict__ qkv_w, const float* __restrict__ proj_w,
    ushort_t* __restrict__ wq, ushort_t* __restrict__ wp) {
  int idx = (blockIdx.x * 256 + threadIdx.x) * 4;
  const int N1 = 3 * CC * CC;
  float4 v;
  ushort_t* dst;
  if (idx < N1) {
    v = *(const float4*)(qkv_w + idx);
    dst = wq + idx;
  } else {
    int j = idx - N1;
    v = *(const float4*)(proj_w + j);
    dst = wp + j;
  }
  unsigned lo = f2bf(v.x) | ((unsigned)f2bf(v.y) << 16);
  unsigned hi = f2bf(v.z) | ((unsigned)f2bf(v.w) << 16);
  *(uint2*)dst = make_uint2(lo, hi);
}

// ---------------- GN apply + transpose -> xnT[b][l][c] bf16 ----------------
__global__ __launch_bounds__(256) void xnt_kernel(
    const float* __restrict__ x, const float* __restrict__ s_bc,
    const float* __restrict__ t_bc, ushort_t* __restrict__ xnT) {
  const int b = blockIdx.z;
  const int c0 = blockIdx.y * 64;
  const int l0 = blockIdx.x * 64;
  const int tid = threadIdx.x;
  __shared__ ushort_t Ts[64 * 72];
#pragma unroll
  for (int r4 = 0; r4 < 4; ++r4) {
    int c_local = (tid >> 4) + r4 * 16;
    int l_local = (tid & 15) * 4;
    int c = c0 + c_local;
    float sc = s_bc[b * CC + c], sh = t_bc[b * CC + c];
    float4 v = *(const float4*)(x + ((size_t)b * CC + c) * LL + l0 + l_local);
    float vv[4] = {v.x, v.y, v.z, v.w};
#pragma unroll
    for (int dl = 0; dl < 4; ++dl) {
      int l = l_local + dl;
      int cs = c_local ^ (((l >> 2) & 7) << 3);
      Ts[l * 72 + cs] = f2bf(vv[dl] * sc + sh);
    }
  }
  __syncthreads();
#pragma unroll
  for (int rep = 0; rep < 2; ++rep) {
    int gid = tid + rep * 256;
    int l = gid >> 3, seg = gid & 7;
    uint4 v = *(const uint4*)&Ts[l * 72 + ((seg * 8) ^ (((l >> 2) & 7) << 3))];
    *(uint4*)(xnT + ((size_t)b * LL + l0 + l) * CC + c0 + seg * 8) = v;
  }
}

// ---------------- QKV GEMM: bf16 MFMA 128x128 tiles ----------------
__global__ __launch_bounds__(256) void qkv_mfma_kernel(
    const ushort_t* __restrict__ wq, const ushort_t* __restrict__ xnT,
    const float* __restrict__ qkv_b, ushort_t* __restrict__ qT,
    ushort_t* __restrict__ kT, ushort_t* __restrict__ vbuf) {
  const int b = blockIdx.z;
  const int m0 = blockIdx.y * 128;
  const int n0 = blockIdx.x * 128;
  const int tid = threadIdx.x;
  const int w = tid >> 6, lane = tid & 63;
  const int col = lane & 15, quad = lane >> 4;
  const int wm = (w >> 1) * 64, wn = (w & 1) * 64;
  __shared__ ushort_t Smem[2 * 128 * 64];
  ushort_t* As = Smem;
  ushort_t* Bs = Smem + 128 * 64;
  f32x4 acc[4][4];
  f32x4 z = {0.f, 0.f, 0.f, 0.f};
#pragma unroll
  for (int i = 0; i < 4; ++i)
#pragma unroll
    for (int j = 0; j < 4; ++j) acc[i][j] = z;

  for (int k0 = 0; k0 < CC; k0 += 64) {
    __syncthreads();
#pragma unroll
    for (int rep = 0; rep < 4; ++rep) {
      int gid = tid + rep * 256;
      int r = gid >> 3, g = gid & 7;
      uint4 av = *(const uint4*)(wq + (size_t)(m0 + r) * CC + k0 + g * 8);
      *(uint4*)&As[swz(r, g * 8)] = av;
      uint4 bv =
          *(const uint4*)(xnT + ((size_t)b * LL + n0 + r) * CC + k0 + g * 8);
      *(uint4*)&Bs[swz(r, g * 8)] = bv;
    }
    __syncthreads();
#pragma unroll
    for (int kk = 0; kk < 2; ++kk) {
      short8 af[4], bf[4];
#pragma unroll
      for (int mi = 0; mi < 4; ++mi)
        af[mi] = *(const short8*)&As[swz(wm + mi * 16 + col, kk * 32 + quad * 8)];
#pragma unroll
      for (int ni = 0; ni < 4; ++ni)
        bf[ni] = *(const short8*)&Bs[swz(wn + ni * 16 + col, kk * 32 + quad * 8)];
#pragma unroll
      for (int mi = 0; mi < 4; ++mi)
#pragma unroll
        for (int ni = 0; ni < 4; ++ni)
          acc[mi][ni] = __builtin_amdgcn_mfma_f32_16x16x32_bf16(
              af[mi], bf[ni], acc[mi][ni], 0, 0, 0);
    }
  }
  __syncthreads();
  const int chunk_g = (m0 >> 6) + (w >> 1);
  const int sel = chunk_g % 3;
  ushort_t* Tile = Smem + (w >> 1) * 8192;
  if (sel < 2) {
    const float sc = (sel == 0) ? SCALE_Q : 1.f;
#pragma unroll
    for (int mi = 0; mi < 4; ++mi) {
      int mg = m0 + wm + mi * 16 + quad * 4;
      float b0 = qkv_b[mg + 0], b1 = qkv_b[mg + 1];
      float b2 = qkv_b[mg + 2], b3 = qkv_b[mg + 3];
      int ch = mi * 16 + quad * 4;
#pragma unroll
      for (int ni = 0; ni < 4; ++ni) {
        int lloc = wn + ni * 16 + col;
        float v0 = (acc[mi][ni][0] + b0) * sc;
        float v1 = (acc[mi][ni][1] + b1) * sc;
        float v2 = (acc[mi][ni][2] + b2) * sc;
        float v3 = (acc[mi][ni][3] + b3) * sc;
        int chs = ch ^ ((lloc & 7) << 3);
        *(uint2*)&Tile[lloc * 64 + chs] =
            make_uint2(pack_bf2(v0, v1), pack_bf2(v2, v3));
      }
    }
  } else {
#pragma unroll
    for (int mi = 0; mi < 4; ++mi)
#pragma unroll
      for (int r = 0; r < 4; ++r) {
        int ch = mi * 16 + quad * 4 + r;
        float bias = qkv_b[m0 + wm + ch];
#pragma unroll
        for (int ni = 0; ni < 4; ++ni) {
          int lloc = wn + ni * 16 + col;
          Tile[ch * 128 + lloc] =
              (ushort_t)(__float_as_uint(acc[mi][ni][r] + bias) >> 16);
        }
      }
  }
  __syncthreads();
#pragma unroll
  for (int ci = 0; ci < 2; ++ci) {
    int cg = (m0 >> 6) + ci;
    int head = cg / 3, sel2 = cg % 3;
    int bh = b * NH + head;
    ushort_t* T2 = Smem + ci * 8192;
    if (sel2 < 2) {
      ushort_t* dst = (sel2 == 0) ? qT : kT;
#pragma unroll
      for (int it = 0; it < 4; ++it) {
        int idx = tid + it * 256;
        int l = idx >> 3, seg = idx & 7;
        uint4 v = *(const uint4*)&T2[l * 64 + ((seg * 8) ^ ((l & 7) << 3))];
        *(uint4*)(dst + ((size_t)bh * LL + n0 + l) * CH + seg * 8) = v;
      }
    } else {
#pragma unroll
      for (int it = 0; it < 4; ++it) {
        int idx = tid + it * 256;
        int ch = idx >> 4, lseg = idx & 15;
        uint4 v = *(const uint4*)&T2[ch * 128 + lseg * 8];
        *(uint4*)(vbuf + ((size_t)bh * CH + ch) * LL + n0 + lseg * 8) = v;
      }
    }
  }
}

// ---- Flash attention: barrier-free. K/V/Q fragments loaded directly from
// global (L1/L2-cached); only P transits LDS, in wave-private strips. ----
__global__ __launch_bounds__(256) void attn_mfma_kernel(
    const ushort_t* __restrict__ qT, const ushort_t* __restrict__ kT,
    const ushort_t* __restrict__ vbuf, ushort_t* __restrict__ abuf) {
  // 512 blocks; XCD (B&7) owns 8 bh -> K/V working set 2MB in its L2
  const int B = blockIdx.x;
  const int j = B >> 3;
  const int bh = (B & 7) * 8 + (j & 7);
  const int tg = j >> 3;  // 0..7, block's 128-t group
  const int b = bh >> 3, h = bh & 7;
  const int tid = threadIdx.x;
  const int w = tid >> 6, lane = tid & 63;
  const int col = lane & 15, quad = lane >> 4;
  const int tb = tg * 128 + w * 32;  // wave's 32 t-rows
  // P strips: per wave 2 strips x 16 rows x stride 72 (uniform banking)
  __shared__ ushort_t Ps[4 * 2304];
  ushort_t* pw = &Ps[w * 2304];

  const ushort_t* qb = qT + (size_t)bh * LL * CH;
  const ushort_t* kb = kT + (size_t)bh * LL * CH;
  const ushort_t* vbp = vbuf + (size_t)bh * CH * LL;

  // Q fragments straight from global, live in regs all kernel
  short8 bq[2][2];
#pragma unroll
  for (int st = 0; st < 2; ++st)
#pragma unroll
    for (int kk = 0; kk < 2; ++kk)
      bq[st][kk] = *(const short8*)(qb + (size_t)(tb + st * 16 + col) * CH +
                                    kk * 32 + quad * 8);

  f32x4 z = {0.f, 0.f, 0.f, 0.f};
  float m_s[2] = {0.f, 0.f};
  float lsum[2] = {0.f, 0.f};
  f32x4 oacc[2][4];
#pragma unroll
  for (int st = 0; st < 2; ++st)
#pragma unroll
    for (int ci = 0; ci < 4; ++ci) oacc[st][ci] = z;

  // prefetch tile-0 K fragments
  short8 ak[4][2];
#pragma unroll
  for (int si = 0; si < 4; ++si)
#pragma unroll
    for (int kk = 0; kk < 2; ++kk)
      ak[si][kk] = *(const short8*)(kb + (size_t)(si * 16 + col) * CH +
                                    kk * 32 + quad * 8);

  for (int it = 0; it < 16; ++it) {
    const int s0 = it * 64;
    // V fragments for this tile (needed only at PV -> long slack)
    short8 bv[4][2];
#pragma unroll
    for (int ci = 0; ci < 4; ++ci)
#pragma unroll
      for (int kk = 0; kk < 2; ++kk)
        bv[ci][kk] = *(const short8*)(vbp + (size_t)(ci * 16 + col) * LL + s0 +
                                      kk * 32 + quad * 8);
    // S^T[s][t] = K Q^T (q pre-scaled by 0.125*log2e)
    f32x4 sacc[2][4];
#pragma unroll
    for (int st = 0; st < 2; ++st)
#pragma unroll
      for (int si = 0; si < 4; ++si) sacc[st][si] = z;
#pragma unroll
    for (int kk = 0; kk < 2; ++kk)
#pragma unroll
      for (int si = 0; si < 4; ++si)
#pragma unroll
        for (int st = 0; st < 2; ++st)
          sacc[st][si] = __builtin_amdgcn_mfma_f32_16x16x32_bf16(
              ak[si][kk], bq[st][kk], sacc[st][si], 0, 0, 0);
    // prefetch next tile's K fragments (latency hidden under softmax+PV)
    if (it < 15) {
      const int sn = s0 + 64;
#pragma unroll
      for (int si = 0; si < 4; ++si)
#pragma unroll
        for (int kk = 0; kk < 2; ++kk)
          ak[si][kk] = *(const short8*)(kb + (size_t)(sn + si * 16 + col) * CH +
                                        kk * 32 + quad * 8);
    }
    if (it == 0) {  // freeze softmax shift at tile-0 max (range-safe)
#pragma unroll
      for (int st = 0; st < 2; ++st) {
        float mx = sacc[st][0][0];
#pragma unroll
        for (int si = 0; si < 4; ++si)
#pragma unroll
          for (int r = 0; r < 4; ++r) mx = fmaxf(mx, sacc[st][si][r]);
        mx = fmaxf(mx, __shfl_xor(mx, 16));
        mx = fmaxf(mx, __shfl_xor(mx, 32));
        m_s[st] = mx;
      }
    }
    // p = exp2(S - m); write P strip [t=col][s], stride 72
#pragma unroll
    for (int st = 0; st < 2; ++st)
#pragma unroll
      for (int si = 0; si < 4; ++si) {
        float p0 = __builtin_amdgcn_exp2f(sacc[st][si][0] - m_s[st]);
        float p1 = __builtin_amdgcn_exp2f(sacc[st][si][1] - m_s[st]);
        float p2 = __builtin_amdgcn_exp2f(sacc[st][si][2] - m_s[st]);
        float p3 = __builtin_amdgcn_exp2f(sacc[st][si][3] - m_s[st]);
        lsum[st] += (p0 + p1) + (p2 + p3);
        *(uint2*)&pw[st * 1152 + col * 72 + si * 16 + quad * 4] =
            make_uint2(pack_bf2(p0, p1), pack_bf2(p2, p3));
      }
    // O += P V^T (wave-private P strip; compiler orders via lgkmcnt)
#pragma unroll
    for (int kk = 0; kk < 2; ++kk) {
      short8 ap[2];
#pragma unroll
      for (int st = 0; st < 2; ++st)
        ap[st] = *(const short8*)&pw[st * 1152 + col * 72 + kk * 32 + quad * 8];
#pragma unroll
      for (int ci = 0; ci < 4; ++ci)
#pragma unroll
        for (int st = 0; st < 2; ++st)
          oacc[st][ci] = __builtin_amdgcn_mfma_f32_16x16x32_bf16(
              ap[st], bv[ci][kk], oacc[st][ci], 0, 0, 0);
    }
  }
  // normalize + write abuf[b][l][h*64+c] bf16
#pragma unroll
  for (int st = 0; st < 2; ++st) {
    float ls = lsum[st];
    ls += __shfl_xor(ls, 16);
    ls += __shfl_xor(ls, 32);
    float linv[4];
#pragma unroll
    for (int r = 0; r < 4; ++r)
      linv[r] = 1.f / __shfl(ls, (lane & 48) | (quad * 4 + r), 64);
#pragma unroll
    for (int r = 0; r < 4; ++r) {
      int l = tb + st * 16 + quad * 4 + r;
#pragma unroll
      for (int ci = 0; ci < 4; ++ci) {
        int c = h * CH + ci * 16 + col;
        abuf[((size_t)b * LL + l) * CC + c] = f2bf(oacc[st][ci][r] * linv[r]);
      }
    }
  }
}

// ---------------- proj GEMM + bias + residual (64m x 128n tiles) ----------------
__global__ __launch_bounds__(256) void proj_mfma_kernel(
    const ushort_t* __restrict__ wp, const ushort_t* __restrict__ abuf,
    const float* __restrict__ proj_b, const float* __restrict__ x,
    float* __restrict__ out) {
  const int b = blockIdx.z;
  const int m0 = blockIdx.y * 64;
  const int n0 = blockIdx.x * 128;
  const int tid = threadIdx.x;
  const int w = tid >> 6, lane = tid & 63;
  const int col = lane & 15, quad = lane >> 4;
  const int wm = (w >> 1) * 32, wn = (w & 1) * 64;
  __shared__ ushort_t As[64 * 64];
  __shared__ ushort_t Bs[128 * 64];
  f32x4 acc[2][4];
  f32x4 z = {0.f, 0.f, 0.f, 0.f};
#pragma unroll
  for (int i = 0; i < 2; ++i)
#pragma unroll
    for (int j = 0; j < 4; ++j) acc[i][j] = z;

  for (int k0 = 0; k0 < CC; k0 += 64) {
    __syncthreads();
#pragma unroll
    for (int rep = 0; rep < 2; ++rep) {
      int idx = tid + rep * 256;
      int r = idx >> 3, g = idx & 7;
      uint4 av = *(const uint4*)(wp + (size_t)(m0 + r) * CC + k0 + g * 8);
      *(uint4*)&As[swz(r, g * 8)] = av;
    }
#pragma unroll
    for (int rep = 0; rep < 4; ++rep) {
      int idx = tid + rep * 256;
      int r = idx >> 3, g = idx & 7;
      uint4 bv =
          *(const uint4*)(abuf + ((size_t)b * LL + n0 + r) * CC + k0 + g * 8);
      *(uint4*)&Bs[swz(r, g * 8)] = bv;
    }
    __syncthreads();
#pragma unroll
    for (int kk = 0; kk < 2; ++kk) {
      short8 af[2], bf[4];
#pragma unroll
      for (int mi = 0; mi < 2; ++mi)
        af[mi] = *(const short8*)&As[swz(wm + mi * 16 + col, kk * 32 + quad * 8)];
#pragma unroll
      for (int ni = 0; ni < 4; ++ni)
        bf[ni] = *(const short8*)&Bs[swz(wn + ni * 16 + col, kk * 32 + quad * 8)];
#pragma unroll
      for (int mi = 0; mi < 2; ++mi)
#pragma unroll
        for (int ni = 0; ni < 4; ++ni)
          acc[mi][ni] = __builtin_amdgcn_mfma_f32_16x16x32_bf16(
              af[mi], bf[ni], acc[mi][ni], 0, 0, 0);
    }
  }
#pragma unroll
  for (int mi = 0; mi < 2; ++mi)
#pragma unroll
    for (int r = 0; r < 4; ++r) {
      int o = m0 + wm + mi * 16 + quad * 4 + r;
      float bias = proj_b[o];
#pragma unroll
      for (int ni = 0; ni < 4; ++ni) {
        int l = n0 + wn + ni * 16 + col;
        size_t off = ((size_t)b * CC + o) * LL + l;
        out[off] = x[off] + bias + acc[mi][ni][r];
      }
    }
}

extern "C" void kernel_launch(void* const* d_in, const int* in_sizes, int n_in,
                              void* d_out, int out_size, void* d_ws,
                              size_t ws_size, hipStream_t stream) {
  const float* x = (const float*)d_in[0];
  const float* gn_w = (const float*)d_in[1];
  const float* gn_b = (const float*)d_in[2];
  const float* qkv_w = (const float*)d_in[3];
  const float* qkv_b = (const float*)d_in[4];
  const float* proj_w = (const float*)d_in[5];
  const float* proj_b = (const float*)d_in[6];
  float* out = (float*)d_out;

  char* ws = (char*)d_ws;
  float* s_bc = (float*)ws;
  float* t_bc = s_bc + BB * CC;
  ushort_t* wq = (ushort_t*)(t_bc + BB * CC);
  ushort_t* wp = wq + (size_t)3 * CC * CC;
  ushort_t* xnT = wp + (size_t)CC * CC;
  ushort_t* qT = xnT + (size_t)BB * LL * CC;
  ushort_t* kT = qT + (size_t)BB * NH * LL * CH;
  ushort_t* vb = kT + (size_t)BB * NH * LL * CH;
  ushort_t* abuf = vb + (size_t)BB * NH * LL * CH;

  gn_stats_kernel<<<BB * GG, 256, 0, stream>>>(x, gn_w, gn_b, s_bc, t_bc);
  convert_w_kernel<<<1024, 256, 0, stream>>>(qkv_w, proj_w, wq, wp);
  xnt_kernel<<<dim3(LL / 64, CC / 64, BB), 256, 0, stream>>>(x, s_bc, t_bc,
                                                             xnT);
  qkv_mfma_kernel<<<dim3(LL / 128, (3 * CC) / 128, BB), 256, 0, stream>>>(
      wq, xnT, qkv_b, qT, kT, vb);
  attn_mfma_kernel<<<dim3(512), 256, 0, stream>>>(qT, kT, vb, abuf);
  proj_mfma_kernel<<<dim3(LL / 128, CC / 64, BB), 256, 0, stream>>>(
      wp, abuf, proj_b, x, out);
}

// Round 8
// 169.925 us; speedup vs baseline: 1.1743x; 1.1743x over previous
//
#include <hip/hip_runtime.h>
#include <math.h>

#define BB 8
#define CC 512
#define LL 1024
#define GG 32
#define CPG 16
#define NH 8
#define CH 64

typedef unsigned short ushort_t;
typedef __attribute__((ext_vector_type(8))) short short8;
typedef __attribute__((ext_vector_type(4))) float f32x4;

#define SCALE_Q 0.18033688f  // 0.125 * log2(e)

typedef __attribute__((address_space(3))) unsigned as3_u32;
typedef __attribute__((address_space(1))) unsigned as1_u32;

// async global->LDS, 16B per lane; lds dest = wave-uniform base + lane*16
__device__ inline void async_copy16(ushort_t* lds, const ushort_t* g) {
  __builtin_amdgcn_global_load_lds((const as1_u32*)g, (as3_u32*)lds, 16, 0, 0);
}

__device__ inline ushort_t f2bf(float f) {
  union { float f; unsigned u; } v;
  v.f = f;
  unsigned r = v.u + 0x7FFFu + ((v.u >> 16) & 1u);
  return (ushort_t)(r >> 16);
}

// pack two f32 -> two bf16 (truncate) in one v_perm_b32
__device__ inline unsigned pack_bf2(float lo, float hi) {
  return __builtin_amdgcn_perm(__float_as_uint(hi), __float_as_uint(lo),
                               0x07060302u);
}

// XOR-swizzled LDS index (used by attention + epilogues only)
__device__ inline int swz(int r, int k) {
  return r * 64 + ((((k >> 3) ^ (r & 7)) << 3) | (k & 7));
}

// ---------------- GroupNorm stats -> per-(b,c) scale/shift ----------------
__global__ __launch_bounds__(256) void gn_stats_kernel(
    const float* __restrict__ x, const float* __restrict__ gn_w,
    const float* __restrict__ gn_b, float* __restrict__ s_bc,
    float* __restrict__ t_bc) {
  int b = blockIdx.x / GG;
  int g = blockIdx.x % GG;
  const float* xg = x + ((size_t)b * CC + (size_t)g * CPG) * LL;
  float sum = 0.f, sq = 0.f;
  for (int i = threadIdx.x; i < CPG * LL; i += 256) {
    float v = xg[i];
    sum += v;
    sq += v * v;
  }
#pragma unroll
  for (int off = 32; off > 0; off >>= 1) {
    sum += __shfl_down(sum, off);
    sq += __shfl_down(sq, off);
  }
  __shared__ float red[8];
  __shared__ float st[2];
  int wave = threadIdx.x >> 6;
  if ((threadIdx.x & 63) == 0) {
    red[wave] = sum;
    red[4 + wave] = sq;
  }
  __syncthreads();
  if (threadIdx.x == 0) {
    float s = red[0] + red[1] + red[2] + red[3];
    float q = red[4] + red[5] + red[6] + red[7];
    float mean = s * (1.f / (CPG * LL));
    float var = q * (1.f / (CPG * LL)) - mean * mean;
    st[0] = mean;
    st[1] = rsqrtf(var + 1e-5f);
  }
  __syncthreads();
  if (threadIdx.x < CPG) {
    int c = g * CPG + threadIdx.x;
    float w = gn_w[c];
    float sc = st[1] * w;
    s_bc[b * CC + c] = sc;
    t_bc[b * CC + c] = gn_b[c] - st[0] * sc;
  }
}

// ---- fused: weight fp32->bf16 conversion (blocks 0..1023) +
//      GN-apply+transpose -> xnT[b][l][c] (blocks 1024..2047) ----
__global__ __launch_bounds__(256) void pre_kernel(
    const float* __restrict__ qkv_w, const float* __restrict__ proj_w,
    ushort_t* __restrict__ wq, ushort_t* __restrict__ wp,
    const float* __restrict__ x, const float* __restrict__ s_bc,
    const float* __restrict__ t_bc, ushort_t* __restrict__ xnT) {
  const int Bx = blockIdx.x;
  const int tid = threadIdx.x;
  __shared__ ushort_t Ts[64 * 72];
  if (Bx < 1024) {
    int idx = (Bx * 256 + tid) * 4;
    const int N1 = 3 * CC * CC;
    float4 v;
    ushort_t* dst;
    if (idx < N1) {
      v = *(const float4*)(qkv_w + idx);
      dst = wq + idx;
    } else {
      int j = idx - N1;
      v = *(const float4*)(proj_w + j);
      dst = wp + j;
    }
    unsigned lo = f2bf(v.x) | ((unsigned)f2bf(v.y) << 16);
    unsigned hi = f2bf(v.z) | ((unsigned)f2bf(v.w) << 16);
    *(uint2*)dst = make_uint2(lo, hi);
    return;
  }
  const int B2 = Bx - 1024;
  const int b = B2 >> 7;
  const int c0 = ((B2 >> 4) & 7) * 64;
  const int l0 = (B2 & 15) * 64;
#pragma unroll
  for (int r4 = 0; r4 < 4; ++r4) {
    int c_local = (tid >> 4) + r4 * 16;
    int l_local = (tid & 15) * 4;
    int c = c0 + c_local;
    float sc = s_bc[b * CC + c], sh = t_bc[b * CC + c];
    float4 v = *(const float4*)(x + ((size_t)b * CC + c) * LL + l0 + l_local);
    float vv[4] = {v.x, v.y, v.z, v.w};
#pragma unroll
    for (int dl = 0; dl < 4; ++dl) {
      int l = l_local + dl;
      int cs = c_local ^ (((l >> 2) & 7) << 3);
      Ts[l * 72 + cs] = f2bf(vv[dl] * sc + sh);
    }
  }
  __syncthreads();
#pragma unroll
  for (int rep = 0; rep < 2; ++rep) {
    int gid = tid + rep * 256;
    int l = gid >> 3, seg = gid & 7;
    uint4 v = *(const uint4*)&Ts[l * 72 + ((seg * 8) ^ (((l >> 2) & 7) << 3))];
    *(uint4*)(xnT + ((size_t)b * LL + l0 + l) * CC + c0 + seg * 8) = v;
  }
}

// ---------------- QKV GEMM: async-staged bf16 MFMA 128x128 tiles ----------------
__global__ __launch_bounds__(256) void qkv_mfma_kernel(
    const ushort_t* __restrict__ wq, const ushort_t* __restrict__ xnT,
    const float* __restrict__ qkv_b, ushort_t* __restrict__ qT,
    ushort_t* __restrict__ kT, ushort_t* __restrict__ vbuf) {
  const int b = blockIdx.z;
  const int m0 = blockIdx.y * 128;
  const int n0 = blockIdx.x * 128;
  const int tid = threadIdx.x;
  const int w = tid >> 6, lane = tid & 63;
  const int col = lane & 15, quad = lane >> 4;
  const int wm = (w >> 1) * 64, wn = (w & 1) * 64;
  __shared__ ushort_t Smem[2 * 128 * 64];
  ushort_t* As = Smem;            // [r][k] linear (async-staged)
  ushort_t* Bs = Smem + 128 * 64;
  f32x4 acc[4][4];
  f32x4 z = {0.f, 0.f, 0.f, 0.f};
#pragma unroll
  for (int i = 0; i < 4; ++i)
#pragma unroll
    for (int j = 0; j < 4; ++j) acc[i][j] = z;

  for (int k0 = 0; k0 < CC; k0 += 64) {
    __syncthreads();
#pragma unroll
    for (int rep = 0; rep < 4; ++rep) {
      int gid = tid + rep * 256;
      int r = gid >> 3, g = gid & 7;
      async_copy16(As + (size_t)(w * 64 + rep * 256) * 8,
                   wq + (size_t)(m0 + r) * CC + k0 + g * 8);
      async_copy16(Bs + (size_t)(w * 64 + rep * 256) * 8,
                   xnT + ((size_t)b * LL + n0 + r) * CC + k0 + g * 8);
    }
    __syncthreads();
#pragma unroll
    for (int kk = 0; kk < 2; ++kk) {
      short8 af[4], bf[4];
#pragma unroll
      for (int mi = 0; mi < 4; ++mi)
        af[mi] =
            *(const short8*)&As[(wm + mi * 16 + col) * 64 + kk * 32 + quad * 8];
#pragma unroll
      for (int ni = 0; ni < 4; ++ni)
        bf[ni] =
            *(const short8*)&Bs[(wn + ni * 16 + col) * 64 + kk * 32 + quad * 8];
#pragma unroll
      for (int mi = 0; mi < 4; ++mi)
#pragma unroll
        for (int ni = 0; ni < 4; ++ni)
          acc[mi][ni] = __builtin_amdgcn_mfma_f32_16x16x32_bf16(
              af[mi], bf[ni], acc[mi][ni], 0, 0, 0);
    }
  }
  __syncthreads();
  const int chunk_g = (m0 >> 6) + (w >> 1);
  const int sel = chunk_g % 3;
  ushort_t* Tile = Smem + (w >> 1) * 8192;
  if (sel < 2) {
    const float sc = (sel == 0) ? SCALE_Q : 1.f;
#pragma unroll
    for (int mi = 0; mi < 4; ++mi) {
      int mg = m0 + wm + mi * 16 + quad * 4;
      float b0 = qkv_b[mg + 0], b1 = qkv_b[mg + 1];
      float b2 = qkv_b[mg + 2], b3 = qkv_b[mg + 3];
      int ch = mi * 16 + quad * 4;
#pragma unroll
      for (int ni = 0; ni < 4; ++ni) {
        int lloc = wn + ni * 16 + col;
        float v0 = (acc[mi][ni][0] + b0) * sc;
        float v1 = (acc[mi][ni][1] + b1) * sc;
        float v2 = (acc[mi][ni][2] + b2) * sc;
        float v3 = (acc[mi][ni][3] + b3) * sc;
        int chs = ch ^ ((lloc & 7) << 3);
        *(uint2*)&Tile[lloc * 64 + chs] =
            make_uint2(pack_bf2(v0, v1), pack_bf2(v2, v3));
      }
    }
  } else {
#pragma unroll
    for (int mi = 0; mi < 4; ++mi)
#pragma unroll
      for (int r = 0; r < 4; ++r) {
        int ch = mi * 16 + quad * 4 + r;
        float bias = qkv_b[m0 + wm + ch];
#pragma unroll
        for (int ni = 0; ni < 4; ++ni) {
          int lloc = wn + ni * 16 + col;
          Tile[ch * 128 + lloc] =
              (ushort_t)(__float_as_uint(acc[mi][ni][r] + bias) >> 16);
        }
      }
  }
  __syncthreads();
#pragma unroll
  for (int ci = 0; ci < 2; ++ci) {
    int cg = (m0 >> 6) + ci;
    int head = cg / 3, sel2 = cg % 3;
    int bh = b * NH + head;
    ushort_t* T2 = Smem + ci * 8192;
    if (sel2 < 2) {
      ushort_t* dst = (sel2 == 0) ? qT : kT;
#pragma unroll
      for (int it = 0; it < 4; ++it) {
        int idx = tid + it * 256;
        int l = idx >> 3, seg = idx & 7;
        uint4 v = *(const uint4*)&T2[l * 64 + ((seg * 8) ^ ((l & 7) << 3))];
        *(uint4*)(dst + ((size_t)bh * LL + n0 + l) * CH + seg * 8) = v;
      }
    } else {
#pragma unroll
      for (int it = 0; it < 4; ++it) {
        int idx = tid + it * 256;
        int ch = idx >> 4, lseg = idx & 15;
        uint4 v = *(const uint4*)&T2[ch * 128 + lseg * 8];
        *(uint4*)(vbuf + ((size_t)bh * CH + ch) * LL + n0 + lseg * 8) = v;
      }
    }
  }
}

// ---------------- Flash attention: R3-exact (best measured) ----------------
__global__ __launch_bounds__(256) void attn_mfma_kernel(
    const ushort_t* __restrict__ qT, const ushort_t* __restrict__ kT,
    const ushort_t* __restrict__ vbuf, ushort_t* __restrict__ abuf) {
  // XCD-aware swizzle: all 16 t-tiles of one bh to the same XCD (L2 reuse)
  const int B = blockIdx.x;
  const int bh = (B & 7) * 8 + ((B >> 3) >> 4);
  const int t0g = ((B >> 3) & 15) * 64;
  const int b = bh >> 3, h = bh & 7;
  const int tid = threadIdx.x;
  const int w = tid >> 6, lane = tid & 63;
  const int col = lane & 15, quad = lane >> 4;
  const int strip = w * 16;
  __shared__ ushort_t QPs[64 * 64];  // Q (B-frag source), then P
  __shared__ ushort_t Ks[64 * 64];
  __shared__ ushort_t Vs[64 * 64];

  // stage Q tile [t][c]
#pragma unroll
  for (int rep = 0; rep < 2; ++rep) {
    int gid = tid + rep * 256;
    int r = gid >> 3, g = gid & 7;
    uint4 v = *(const uint4*)(qT + ((size_t)bh * LL + t0g + r) * CH + g * 8);
    *(uint4*)&QPs[swz(r, g * 8)] = v;
  }
  __syncthreads();
  short8 bq[2];  // Q B-fragment held in registers for the whole kernel
  bq[0] = *(const short8*)&QPs[swz(strip + col, quad * 8)];
  bq[1] = *(const short8*)&QPs[swz(strip + col, 32 + quad * 8)];

  float m_s = 0.f, lsum = 0.f;
  f32x4 oacc[4];
  f32x4 z = {0.f, 0.f, 0.f, 0.f};
#pragma unroll
  for (int ci = 0; ci < 4; ++ci) oacc[ci] = z;

  for (int s0 = 0; s0 < LL; s0 += 64) {
    __syncthreads();
#pragma unroll
    for (int rep = 0; rep < 2; ++rep) {
      int gid = tid + rep * 256;
      int r = gid >> 3, g = gid & 7;
      uint4 kv = *(const uint4*)(kT + ((size_t)bh * LL + s0 + r) * CH + g * 8);
      *(uint4*)&Ks[swz(r, g * 8)] = kv;
      uint4 vv = *(const uint4*)(vbuf + ((size_t)bh * CH + r) * LL + s0 + g * 8);
      *(uint4*)&Vs[swz(r, g * 8)] = vv;
    }
    __syncthreads();
    // S^T[s][t] = K Q^T (q pre-scaled by 0.125*log2e)
    f32x4 sacc[4];
#pragma unroll
    for (int si = 0; si < 4; ++si) sacc[si] = z;
#pragma unroll
    for (int kk = 0; kk < 2; ++kk)
#pragma unroll
      for (int si = 0; si < 4; ++si) {
        short8 ak = *(const short8*)&Ks[swz(si * 16 + col, kk * 32 + quad * 8)];
        sacc[si] =
            __builtin_amdgcn_mfma_f32_16x16x32_bf16(ak, bq[kk], sacc[si], 0, 0, 0);
      }
    if (s0 == 0) {  // freeze softmax shift at tile-0 max (range-safe)
      float mx = sacc[0][0];
#pragma unroll
      for (int si = 0; si < 4; ++si)
#pragma unroll
        for (int r = 0; r < 4; ++r) mx = fmaxf(mx, sacc[si][r]);
      mx = fmaxf(mx, __shfl_xor(mx, 16));
      mx = fmaxf(mx, __shfl_xor(mx, 32));
      m_s = mx;
    }
    // p = exp2(S' - m), accumulate l, pack into Ps ([t][s], swizzled)
#pragma unroll
    for (int si = 0; si < 4; ++si) {
      float p0 = __builtin_amdgcn_exp2f(sacc[si][0] - m_s);
      float p1 = __builtin_amdgcn_exp2f(sacc[si][1] - m_s);
      float p2 = __builtin_amdgcn_exp2f(sacc[si][2] - m_s);
      float p3 = __builtin_amdgcn_exp2f(sacc[si][3] - m_s);
      lsum += (p0 + p1) + (p2 + p3);
      int base = swz(strip + col, si * 16 + quad * 4);
      *(uint2*)&QPs[base] = make_uint2(pack_bf2(p0, p1), pack_bf2(p2, p3));
    }
    // O += P V^T
#pragma unroll
    for (int kk = 0; kk < 2; ++kk) {
      short8 ap = *(const short8*)&QPs[swz(strip + col, kk * 32 + quad * 8)];
#pragma unroll
      for (int ci = 0; ci < 4; ++ci) {
        short8 bv = *(const short8*)&Vs[swz(ci * 16 + col, kk * 32 + quad * 8)];
        oacc[ci] =
            __builtin_amdgcn_mfma_f32_16x16x32_bf16(ap, bv, oacc[ci], 0, 0, 0);
      }
    }
  }
  // full row-sum l at t=strip+col; redistribute to t=strip+quad*4+r
  lsum += __shfl_xor(lsum, 16);
  lsum += __shfl_xor(lsum, 32);
  float linv[4];
#pragma unroll
  for (int r = 0; r < 4; ++r)
    linv[r] = 1.f / __shfl(lsum, (lane & 48) | (quad * 4 + r), 64);
#pragma unroll
  for (int r = 0; r < 4; ++r) {
    int l = t0g + strip + quad * 4 + r;
#pragma unroll
    for (int ci = 0; ci < 4; ++ci) {
      int c = h * CH + ci * 16 + col;
      abuf[((size_t)b * LL + l) * CC + c] = f2bf(oacc[ci][r] * linv[r]);
    }
  }
}

// ------------- proj GEMM + bias + residual (async-staged, 64m x 128n) -------------
__global__ __launch_bounds__(256) void proj_mfma_kernel(
    const ushort_t* __restrict__ wp, const ushort_t* __restrict__ abuf,
    const float* __restrict__ proj_b, const float* __restrict__ x,
    float* __restrict__ out) {
  const int b = blockIdx.z;
  const int m0 = blockIdx.y * 64;
  const int n0 = blockIdx.x * 128;
  const int tid = threadIdx.x;
  const int w = tid >> 6, lane = tid & 63;
  const int col = lane & 15, quad = lane >> 4;
  const int wm = (w >> 1) * 32, wn = (w & 1) * 64;
  __shared__ ushort_t As[64 * 64];   // [r][k] linear
  __shared__ ushort_t Bs[128 * 64];  // [r][k] linear
  f32x4 acc[2][4];
  f32x4 z = {0.f, 0.f, 0.f, 0.f};
#pragma unroll
  for (int i = 0; i < 2; ++i)
#pragma unroll
    for (int j = 0; j < 4; ++j) acc[i][j] = z;

  for (int k0 = 0; k0 < CC; k0 += 64) {
    __syncthreads();
#pragma unroll
    for (int rep = 0; rep < 2; ++rep) {
      int idx = tid + rep * 256;
      int r = idx >> 3, g = idx & 7;
      async_copy16(As + (size_t)(w * 64 + rep * 256) * 8,
                   wp + (size_t)(m0 + r) * CC + k0 + g * 8);
    }
#pragma unroll
    for (int rep = 0; rep < 4; ++rep) {
      int idx = tid + rep * 256;
      int r = idx >> 3, g = idx & 7;
      async_copy16(Bs + (size_t)(w * 64 + rep * 256) * 8,
                   abuf + ((size_t)b * LL + n0 + r) * CC + k0 + g * 8);
    }
    __syncthreads();
#pragma unroll
    for (int kk = 0; kk < 2; ++kk) {
      short8 af[2], bf[4];
#pragma unroll
      for (int mi = 0; mi < 2; ++mi)
        af[mi] =
            *(const short8*)&As[(wm + mi * 16 + col) * 64 + kk * 32 + quad * 8];
#pragma unroll
      for (int ni = 0; ni < 4; ++ni)
        bf[ni] =
            *(const short8*)&Bs[(wn + ni * 16 + col) * 64 + kk * 32 + quad * 8];
#pragma unroll
      for (int mi = 0; mi < 2; ++mi)
#pragma unroll
        for (int ni = 0; ni < 4; ++ni)
          acc[mi][ni] = __builtin_amdgcn_mfma_f32_16x16x32_bf16(
              af[mi], bf[ni], acc[mi][ni], 0, 0, 0);
    }
  }
#pragma unroll
  for (int mi = 0; mi < 2; ++mi)
#pragma unroll
    for (int r = 0; r < 4; ++r) {
      int o = m0 + wm + mi * 16 + quad * 4 + r;
      float bias = proj_b[o];
#pragma unroll
      for (int ni = 0; ni < 4; ++ni) {
        int l = n0 + wn + ni * 16 + col;
        size_t off = ((size_t)b * CC + o) * LL + l;
        out[off] = x[off] + bias + acc[mi][ni][r];
      }
    }
}

extern "C" void kernel_launch(void* const* d_in, const int* in_sizes, int n_in,
                              void* d_out, int out_size, void* d_ws,
                              size_t ws_size, hipStream_t stream) {
  const float* x = (const float*)d_in[0];
  const float* gn_w = (const float*)d_in[1];
  const float* gn_b = (const float*)d_in[2];
  const float* qkv_w = (const float*)d_in[3];
  const float* qkv_b = (const float*)d_in[4];
  const float* proj_w = (const float*)d_in[5];
  const float* proj_b = (const float*)d_in[6];
  float* out = (float*)d_out;

  char* ws = (char*)d_ws;
  float* s_bc = (float*)ws;
  float* t_bc = s_bc + BB * CC;
  ushort_t* wq = (ushort_t*)(t_bc + BB * CC);
  ushort_t* wp = wq + (size_t)3 * CC * CC;
  ushort_t* xnT = wp + (size_t)CC * CC;
  ushort_t* qT = xnT + (size_t)BB * LL * CC;
  ushort_t* kT = qT + (size_t)BB * NH * LL * CH;
  ushort_t* vb = kT + (size_t)BB * NH * LL * CH;
  ushort_t* abuf = vb + (size_t)BB * NH * LL * CH;

  gn_stats_kernel<<<BB * GG, 256, 0, stream>>>(x, gn_w, gn_b, s_bc, t_bc);
  pre_kernel<<<2048, 256, 0, stream>>>(qkv_w, proj_w, wq, wp, x, s_bc, t_bc,
                                       xnT);
  qkv_mfma_kernel<<<dim3(LL / 128, (3 * CC) / 128, BB), 256, 0, stream>>>(
      wq, xnT, qkv_b, qT, kT, vb);
  attn_mfma_kernel<<<dim3(1024), 256, 0, stream>>>(qT, kT, vb, abuf);
  proj_mfma_kernel<<<dim3(LL / 128, CC / 64, BB), 256, 0, stream>>>(
      wp, abuf, proj_b, x, out);
}